// Round 1
// baseline (107.707 us; speedup 1.0000x reference)
//
#include <hip/hip_runtime.h>
#include <hip/hip_bf16.h>

// ChannelMask: per-row exact quantile (linear interp) + >= mask.
// scale: [32, 192, 64, 64] f32 -> rows of n = 786432. pr: int scalar (device).
//
// 3-level radix select (11+11+10 bits) on monotone-mapped u32 keys, per row,
// for both order statistics k and k+1; q = lerp(v_k, v_k1, frac); mask pass.

typedef unsigned int uint32;

__device__ __forceinline__ uint32 fmap(uint32 b) {
    // monotone map: float bits -> ascending u32
    return (b & 0x80000000u) ? ~b : (b | 0x80000000u);
}
__device__ __forceinline__ float finv(uint32 u) {
    uint32 b = (u & 0x80000000u) ? (u & 0x7FFFFFFFu) : ~u;
    return __uint_as_float(b);
}

struct Sel { int found; uint32 bin; uint32 rem; };

// One wave (64 lanes) selects the bin containing rank `target` in hist[0..64*bpl).
__device__ Sel wave_select(const uint32* __restrict__ hist, int bpl, uint32 target) {
    int lane = threadIdx.x & 63;
    uint32 s = 0;
    for (int j = 0; j < bpl; ++j) s += hist[lane * bpl + j];
    uint32 incl = s;
    for (int d = 1; d < 64; d <<= 1) {
        uint32 t = __shfl_up(incl, d, 64);
        if (lane >= d) incl += t;
    }
    uint32 excl = incl - s;
    Sel r; r.found = 0; r.bin = 0; r.rem = 0;
    if (target >= excl && target < excl + s) {
        uint32 rem = target - excl;
        for (int j = 0; j < bpl; ++j) {
            uint32 c = hist[lane * bpl + j];
            if (rem < c) { r.found = 1; r.bin = (uint32)(lane * bpl + j); r.rem = rem; break; }
            rem -= c;
        }
    }
    return r;
}

__global__ void __launch_bounds__(256) hist1_k(const float* __restrict__ x,
                                               uint32* __restrict__ g1, int n4) {
    __shared__ uint32 h[4][2048];
    int row = blockIdx.y;
    for (int i = threadIdx.x; i < 4 * 2048; i += 256) ((uint32*)h)[i] = 0;
    __syncthreads();
    const float4* p = (const float4*)x + (size_t)row * (size_t)n4;
    uint32* hw = h[(threadIdx.x >> 6) & 3];
    for (int i = blockIdx.x * 256 + threadIdx.x; i < n4; i += gridDim.x * 256) {
        float4 v = p[i];
        uint32 u0 = fmap(__float_as_uint(v.x));
        uint32 u1 = fmap(__float_as_uint(v.y));
        uint32 u2 = fmap(__float_as_uint(v.z));
        uint32 u3 = fmap(__float_as_uint(v.w));
        atomicAdd(&hw[u0 >> 21], 1u);
        atomicAdd(&hw[u1 >> 21], 1u);
        atomicAdd(&hw[u2 >> 21], 1u);
        atomicAdd(&hw[u3 >> 21], 1u);
    }
    __syncthreads();
    uint32* gr = g1 + (size_t)row * 2048;
    for (int i = threadIdx.x; i < 2048; i += 256) {
        uint32 s = h[0][i] + h[1][i] + h[2][i] + h[3][i];
        if (s) atomicAdd(&gr[i], s);
    }
}

__global__ void __launch_bounds__(128) scan1_k(const uint32* __restrict__ g1,
                                               const int* __restrict__ prp,
                                               uint32* __restrict__ prefix1,
                                               uint32* __restrict__ rem1, int n) {
    int row = blockIdx.x;
    int tgt = threadIdx.x >> 6;
    int pr = *prp;
    float qf = (float)(1.0 - pr * 0.1);
    qf = fminf(fmaxf(qf, 0.f), 1.f);
    float virt = qf * (float)(n - 1);
    uint32 k = (uint32)floorf(virt);
    uint32 target = k + (uint32)tgt;
    Sel r = wave_select(g1 + (size_t)row * 2048, 32, target);
    if (r.found) { prefix1[row * 2 + tgt] = r.bin; rem1[row * 2 + tgt] = r.rem; }
}

__global__ void __launch_bounds__(256) hist2_k(const float* __restrict__ x,
                                               const uint32* __restrict__ prefix1,
                                               uint32* __restrict__ g2, int n4) {
    __shared__ uint32 h[2][2048];
    int row = blockIdx.y;
    uint32 pA = prefix1[row * 2 + 0];
    uint32 pB = prefix1[row * 2 + 1];
    for (int i = threadIdx.x; i < 2 * 2048; i += 256) ((uint32*)h)[i] = 0;
    __syncthreads();
    const float4* p = (const float4*)x + (size_t)row * (size_t)n4;
    for (int i = blockIdx.x * 256 + threadIdx.x; i < n4; i += gridDim.x * 256) {
        float4 v = p[i];
        uint32 uu[4] = { fmap(__float_as_uint(v.x)), fmap(__float_as_uint(v.y)),
                         fmap(__float_as_uint(v.z)), fmap(__float_as_uint(v.w)) };
#pragma unroll
        for (int e = 0; e < 4; ++e) {
            uint32 hi = uu[e] >> 21, mid = (uu[e] >> 10) & 2047u;
            if (hi == pA) atomicAdd(&h[0][mid], 1u);
            if (hi == pB) atomicAdd(&h[1][mid], 1u);
        }
    }
    __syncthreads();
    for (int i = threadIdx.x; i < 2048; i += 256) {
        if (h[0][i]) atomicAdd(&g2[((size_t)(row * 2 + 0)) * 2048 + i], h[0][i]);
        if (h[1][i]) atomicAdd(&g2[((size_t)(row * 2 + 1)) * 2048 + i], h[1][i]);
    }
}

__global__ void __launch_bounds__(128) scan2_k(const uint32* __restrict__ g2,
                                               const uint32* __restrict__ prefix1,
                                               const uint32* __restrict__ rem1,
                                               uint32* __restrict__ prefix2,
                                               uint32* __restrict__ rem2) {
    int row = blockIdx.x;
    int tgt = threadIdx.x >> 6;
    uint32 target = rem1[row * 2 + tgt];
    Sel r = wave_select(g2 + (size_t)(row * 2 + tgt) * 2048, 32, target);
    if (r.found) {
        prefix2[row * 2 + tgt] = (prefix1[row * 2 + tgt] << 11) | r.bin;
        rem2[row * 2 + tgt] = r.rem;
    }
}

__global__ void __launch_bounds__(256) hist3_k(const float* __restrict__ x,
                                               const uint32* __restrict__ prefix2,
                                               uint32* __restrict__ g3, int n4) {
    __shared__ uint32 h[2][1024];
    int row = blockIdx.y;
    uint32 pA = prefix2[row * 2 + 0];
    uint32 pB = prefix2[row * 2 + 1];
    for (int i = threadIdx.x; i < 2 * 1024; i += 256) ((uint32*)h)[i] = 0;
    __syncthreads();
    const float4* p = (const float4*)x + (size_t)row * (size_t)n4;
    for (int i = blockIdx.x * 256 + threadIdx.x; i < n4; i += gridDim.x * 256) {
        float4 v = p[i];
        uint32 uu[4] = { fmap(__float_as_uint(v.x)), fmap(__float_as_uint(v.y)),
                         fmap(__float_as_uint(v.z)), fmap(__float_as_uint(v.w)) };
#pragma unroll
        for (int e = 0; e < 4; ++e) {
            uint32 hi = uu[e] >> 10, lo = uu[e] & 1023u;
            if (hi == pA) atomicAdd(&h[0][lo], 1u);
            if (hi == pB) atomicAdd(&h[1][lo], 1u);
        }
    }
    __syncthreads();
    for (int i = threadIdx.x; i < 1024; i += 256) {
        if (h[0][i]) atomicAdd(&g3[((size_t)(row * 2 + 0)) * 1024 + i], h[0][i]);
        if (h[1][i]) atomicAdd(&g3[((size_t)(row * 2 + 1)) * 1024 + i], h[1][i]);
    }
}

__global__ void __launch_bounds__(128) scan3_k(const uint32* __restrict__ g3,
                                               const uint32* __restrict__ prefix2,
                                               const uint32* __restrict__ rem2,
                                               const int* __restrict__ prp,
                                               float* __restrict__ qarr, int n) {
    __shared__ float sval[2];
    int row = blockIdx.x;
    int tgt = threadIdx.x >> 6;
    if (threadIdx.x < 2) sval[threadIdx.x] = 0.f;
    __syncthreads();
    uint32 target = rem2[row * 2 + tgt];
    Sel r = wave_select(g3 + (size_t)(row * 2 + tgt) * 1024, 16, target);
    if (r.found) {
        uint32 ufull = (prefix2[row * 2 + tgt] << 10) | r.bin;
        sval[tgt] = finv(ufull);
    }
    __syncthreads();
    if (threadIdx.x == 0) {
        int pr = *prp;
        float qf = (float)(1.0 - pr * 0.1);
        qf = fminf(fmaxf(qf, 0.f), 1.f);
        float virt = qf * (float)(n - 1);
        float frac = virt - floorf(virt);
        double qd = (double)sval[0] * (double)(1.0f - frac) +
                    (double)sval[1] * (double)frac;
        qarr[row] = (float)qd;
    }
}

__global__ void __launch_bounds__(256) mask_k(const float4* __restrict__ x,
                                              const float* __restrict__ qarr,
                                              const int* __restrict__ prp,
                                              float4* __restrict__ out, int n4) {
    int row = blockIdx.y;
    int pr = *prp;
    const float4* p = x + (size_t)row * (size_t)n4;
    float4* o = out + (size_t)row * (size_t)n4;
    int stride = gridDim.x * 256;
    if (pr >= 10) {
        float4 one = make_float4(1.f, 1.f, 1.f, 1.f);
        for (int i = blockIdx.x * 256 + threadIdx.x; i < n4; i += stride) o[i] = one;
        return;
    }
    if (pr <= 0) {
        float4 zero = make_float4(0.f, 0.f, 0.f, 0.f);
        for (int i = blockIdx.x * 256 + threadIdx.x; i < n4; i += stride) o[i] = zero;
        return;
    }
    float q = qarr[row];
    for (int i = blockIdx.x * 256 + threadIdx.x; i < n4; i += stride) {
        float4 v = p[i];
        float4 r;
        r.x = (v.x >= q) ? 1.f : 0.f;
        r.y = (v.y >= q) ? 1.f : 0.f;
        r.z = (v.z >= q) ? 1.f : 0.f;
        r.w = (v.w >= q) ? 1.f : 0.f;
        o[i] = r;
    }
}

extern "C" void kernel_launch(void* const* d_in, const int* in_sizes, int n_in,
                              void* d_out, int out_size, void* d_ws, size_t ws_size,
                              hipStream_t stream) {
    const float* x = (const float*)d_in[0];
    const int* prp = (const int*)d_in[1];
    float* out = (float*)d_out;

    const int BS = 32;
    int total = in_sizes[0];     // 25165824
    int n = total / BS;          // 786432 per row
    int n4 = n / 4;              // 196608

    uint32* ws = (uint32*)d_ws;
    uint32* g1 = ws;                       // 32*2048       = 65536
    uint32* g2 = g1 + 65536;               // 32*2*2048     = 131072
    uint32* g3 = g2 + 131072;              // 32*2*1024     = 65536
    uint32* prefix1 = g3 + 65536;          // 64
    uint32* rem1 = prefix1 + 64;           // 64
    uint32* prefix2 = rem1 + 64;           // 64
    uint32* rem2 = prefix2 + 64;           // 64
    float* qarr = (float*)(rem2 + 64);     // 32

    size_t wsbytes = (size_t)(65536 + 131072 + 65536 + 64 * 4 + 32) * 4;
    hipMemsetAsync(d_ws, 0, wsbytes, stream);

    hist1_k<<<dim3(48, BS), 256, 0, stream>>>(x, g1, n4);
    scan1_k<<<BS, 128, 0, stream>>>(g1, prp, prefix1, rem1, n);
    hist2_k<<<dim3(48, BS), 256, 0, stream>>>(x, prefix1, g2, n4);
    scan2_k<<<BS, 128, 0, stream>>>(g2, prefix1, rem1, prefix2, rem2);
    hist3_k<<<dim3(48, BS), 256, 0, stream>>>(x, prefix2, g3, n4);
    scan3_k<<<BS, 128, 0, stream>>>(g3, prefix2, rem2, prp, qarr, n);
    mask_k<<<dim3(96, BS), 256, 0, stream>>>((const float4*)x, qarr, prp, (float4*)out, n4);
}

// Round 2
// 107.392 us; speedup vs baseline: 1.0029x; 1.0029x over previous
//
#include <hip/hip_runtime.h>
#include <hip/hip_bf16.h>

// ChannelMask: per-row exact quantile (linear interp) + >= mask.
// scale: [32, 192, 64, 64] f32 -> rows of n = 786432. pr: int scalar (device).
//
// 3-level radix select (11+11+10 bits) on monotone-mapped u32 keys, per row,
// for both order statistics k and k+1; q = lerp(v_k, v_k1, frac); mask pass.
// R1: replaced hipMemsetAsync (57us runtime fill kernel!) with custom zero_k.

typedef unsigned int uint32;

__device__ __forceinline__ uint32 fmap(uint32 b) {
    // monotone map: float bits -> ascending u32
    return (b & 0x80000000u) ? ~b : (b | 0x80000000u);
}
__device__ __forceinline__ float finv(uint32 u) {
    uint32 b = (u & 0x80000000u) ? (u & 0x7FFFFFFFu) : ~u;
    return __uint_as_float(b);
}

struct Sel { int found; uint32 bin; uint32 rem; };

// One wave (64 lanes) selects the bin containing rank `target` in hist[0..64*bpl).
__device__ Sel wave_select(const uint32* __restrict__ hist, int bpl, uint32 target) {
    int lane = threadIdx.x & 63;
    uint32 s = 0;
    for (int j = 0; j < bpl; ++j) s += hist[lane * bpl + j];
    uint32 incl = s;
    for (int d = 1; d < 64; d <<= 1) {
        uint32 t = __shfl_up(incl, d, 64);
        if (lane >= d) incl += t;
    }
    uint32 excl = incl - s;
    Sel r; r.found = 0; r.bin = 0; r.rem = 0;
    if (target >= excl && target < excl + s) {
        uint32 rem = target - excl;
        for (int j = 0; j < bpl; ++j) {
            uint32 c = hist[lane * bpl + j];
            if (rem < c) { r.found = 1; r.bin = (uint32)(lane * bpl + j); r.rem = rem; break; }
            rem -= c;
        }
    }
    return r;
}

__global__ void __launch_bounds__(256) zero_k(uint32* __restrict__ ws, int nwords) {
    int i = blockIdx.x * 256 + threadIdx.x;
    if (i < nwords) ws[i] = 0;
}

__global__ void __launch_bounds__(256) hist1_k(const float* __restrict__ x,
                                               uint32* __restrict__ g1, int n4) {
    __shared__ uint32 h[4][2048];
    int row = blockIdx.y;
    for (int i = threadIdx.x; i < 4 * 2048; i += 256) ((uint32*)h)[i] = 0;
    __syncthreads();
    const float4* p = (const float4*)x + (size_t)row * (size_t)n4;
    uint32* hw = h[(threadIdx.x >> 6) & 3];
    for (int i = blockIdx.x * 256 + threadIdx.x; i < n4; i += gridDim.x * 256) {
        float4 v = p[i];
        uint32 u0 = fmap(__float_as_uint(v.x));
        uint32 u1 = fmap(__float_as_uint(v.y));
        uint32 u2 = fmap(__float_as_uint(v.z));
        uint32 u3 = fmap(__float_as_uint(v.w));
        atomicAdd(&hw[u0 >> 21], 1u);
        atomicAdd(&hw[u1 >> 21], 1u);
        atomicAdd(&hw[u2 >> 21], 1u);
        atomicAdd(&hw[u3 >> 21], 1u);
    }
    __syncthreads();
    uint32* gr = g1 + (size_t)row * 2048;
    for (int i = threadIdx.x; i < 2048; i += 256) {
        uint32 s = h[0][i] + h[1][i] + h[2][i] + h[3][i];
        if (s) atomicAdd(&gr[i], s);
    }
}

__global__ void __launch_bounds__(128) scan1_k(const uint32* __restrict__ g1,
                                               const int* __restrict__ prp,
                                               uint32* __restrict__ prefix1,
                                               uint32* __restrict__ rem1, int n) {
    int row = blockIdx.x;
    int tgt = threadIdx.x >> 6;
    int pr = *prp;
    float qf = (float)(1.0 - pr * 0.1);
    qf = fminf(fmaxf(qf, 0.f), 1.f);
    float virt = qf * (float)(n - 1);
    uint32 k = (uint32)floorf(virt);
    uint32 target = k + (uint32)tgt;
    Sel r = wave_select(g1 + (size_t)row * 2048, 32, target);
    if (r.found) { prefix1[row * 2 + tgt] = r.bin; rem1[row * 2 + tgt] = r.rem; }
}

__global__ void __launch_bounds__(256) hist2_k(const float* __restrict__ x,
                                               const uint32* __restrict__ prefix1,
                                               uint32* __restrict__ g2, int n4) {
    __shared__ uint32 h[2][2048];
    int row = blockIdx.y;
    uint32 pA = prefix1[row * 2 + 0];
    uint32 pB = prefix1[row * 2 + 1];
    for (int i = threadIdx.x; i < 2 * 2048; i += 256) ((uint32*)h)[i] = 0;
    __syncthreads();
    const float4* p = (const float4*)x + (size_t)row * (size_t)n4;
    for (int i = blockIdx.x * 256 + threadIdx.x; i < n4; i += gridDim.x * 256) {
        float4 v = p[i];
        uint32 uu[4] = { fmap(__float_as_uint(v.x)), fmap(__float_as_uint(v.y)),
                         fmap(__float_as_uint(v.z)), fmap(__float_as_uint(v.w)) };
#pragma unroll
        for (int e = 0; e < 4; ++e) {
            uint32 hi = uu[e] >> 21, mid = (uu[e] >> 10) & 2047u;
            if (hi == pA) atomicAdd(&h[0][mid], 1u);
            if (hi == pB) atomicAdd(&h[1][mid], 1u);
        }
    }
    __syncthreads();
    for (int i = threadIdx.x; i < 2048; i += 256) {
        if (h[0][i]) atomicAdd(&g2[((size_t)(row * 2 + 0)) * 2048 + i], h[0][i]);
        if (h[1][i]) atomicAdd(&g2[((size_t)(row * 2 + 1)) * 2048 + i], h[1][i]);
    }
}

__global__ void __launch_bounds__(128) scan2_k(const uint32* __restrict__ g2,
                                               const uint32* __restrict__ prefix1,
                                               const uint32* __restrict__ rem1,
                                               uint32* __restrict__ prefix2,
                                               uint32* __restrict__ rem2) {
    int row = blockIdx.x;
    int tgt = threadIdx.x >> 6;
    uint32 target = rem1[row * 2 + tgt];
    Sel r = wave_select(g2 + (size_t)(row * 2 + tgt) * 2048, 32, target);
    if (r.found) {
        prefix2[row * 2 + tgt] = (prefix1[row * 2 + tgt] << 11) | r.bin;
        rem2[row * 2 + tgt] = r.rem;
    }
}

__global__ void __launch_bounds__(256) hist3_k(const float* __restrict__ x,
                                               const uint32* __restrict__ prefix2,
                                               uint32* __restrict__ g3, int n4) {
    __shared__ uint32 h[2][1024];
    int row = blockIdx.y;
    uint32 pA = prefix2[row * 2 + 0];
    uint32 pB = prefix2[row * 2 + 1];
    for (int i = threadIdx.x; i < 2 * 1024; i += 256) ((uint32*)h)[i] = 0;
    __syncthreads();
    const float4* p = (const float4*)x + (size_t)row * (size_t)n4;
    for (int i = blockIdx.x * 256 + threadIdx.x; i < n4; i += gridDim.x * 256) {
        float4 v = p[i];
        uint32 uu[4] = { fmap(__float_as_uint(v.x)), fmap(__float_as_uint(v.y)),
                         fmap(__float_as_uint(v.z)), fmap(__float_as_uint(v.w)) };
#pragma unroll
        for (int e = 0; e < 4; ++e) {
            uint32 hi = uu[e] >> 10, lo = uu[e] & 1023u;
            if (hi == pA) atomicAdd(&h[0][lo], 1u);
            if (hi == pB) atomicAdd(&h[1][lo], 1u);
        }
    }
    __syncthreads();
    for (int i = threadIdx.x; i < 1024; i += 256) {
        if (h[0][i]) atomicAdd(&g3[((size_t)(row * 2 + 0)) * 1024 + i], h[0][i]);
        if (h[1][i]) atomicAdd(&g3[((size_t)(row * 2 + 1)) * 1024 + i], h[1][i]);
    }
}

__global__ void __launch_bounds__(128) scan3_k(const uint32* __restrict__ g3,
                                               const uint32* __restrict__ prefix2,
                                               const uint32* __restrict__ rem2,
                                               const int* __restrict__ prp,
                                               float* __restrict__ qarr, int n) {
    __shared__ float sval[2];
    int row = blockIdx.x;
    int tgt = threadIdx.x >> 6;
    if (threadIdx.x < 2) sval[threadIdx.x] = 0.f;
    __syncthreads();
    uint32 target = rem2[row * 2 + tgt];
    Sel r = wave_select(g3 + (size_t)(row * 2 + tgt) * 1024, 16, target);
    if (r.found) {
        uint32 ufull = (prefix2[row * 2 + tgt] << 10) | r.bin;
        sval[tgt] = finv(ufull);
    }
    __syncthreads();
    if (threadIdx.x == 0) {
        int pr = *prp;
        float qf = (float)(1.0 - pr * 0.1);
        qf = fminf(fmaxf(qf, 0.f), 1.f);
        float virt = qf * (float)(n - 1);
        float frac = virt - floorf(virt);
        double qd = (double)sval[0] * (double)(1.0f - frac) +
                    (double)sval[1] * (double)frac;
        qarr[row] = (float)qd;
    }
}

__global__ void __launch_bounds__(256) mask_k(const float4* __restrict__ x,
                                              const float* __restrict__ qarr,
                                              const int* __restrict__ prp,
                                              float4* __restrict__ out, int n4) {
    int row = blockIdx.y;
    int pr = *prp;
    const float4* p = x + (size_t)row * (size_t)n4;
    float4* o = out + (size_t)row * (size_t)n4;
    int stride = gridDim.x * 256;
    if (pr >= 10) {
        float4 one = make_float4(1.f, 1.f, 1.f, 1.f);
        for (int i = blockIdx.x * 256 + threadIdx.x; i < n4; i += stride) o[i] = one;
        return;
    }
    if (pr <= 0) {
        float4 zero = make_float4(0.f, 0.f, 0.f, 0.f);
        for (int i = blockIdx.x * 256 + threadIdx.x; i < n4; i += stride) o[i] = zero;
        return;
    }
    float q = qarr[row];
    for (int i = blockIdx.x * 256 + threadIdx.x; i < n4; i += stride) {
        float4 v = p[i];
        float4 r;
        r.x = (v.x >= q) ? 1.f : 0.f;
        r.y = (v.y >= q) ? 1.f : 0.f;
        r.z = (v.z >= q) ? 1.f : 0.f;
        r.w = (v.w >= q) ? 1.f : 0.f;
        o[i] = r;
    }
}

extern "C" void kernel_launch(void* const* d_in, const int* in_sizes, int n_in,
                              void* d_out, int out_size, void* d_ws, size_t ws_size,
                              hipStream_t stream) {
    const float* x = (const float*)d_in[0];
    const int* prp = (const int*)d_in[1];
    float* out = (float*)d_out;

    const int BS = 32;
    int total = in_sizes[0];     // 25165824
    int n = total / BS;          // 786432 per row
    int n4 = n / 4;              // 196608

    uint32* ws = (uint32*)d_ws;
    uint32* g1 = ws;                       // 32*2048       = 65536
    uint32* g2 = g1 + 65536;               // 32*2*2048     = 131072
    uint32* g3 = g2 + 131072;              // 32*2*1024     = 65536
    uint32* prefix1 = g3 + 65536;          // 64
    uint32* rem1 = prefix1 + 64;           // 64
    uint32* prefix2 = rem1 + 64;           // 64
    uint32* rem2 = prefix2 + 64;           // 64
    float* qarr = (float*)(rem2 + 64);     // 32

    int nwords = 65536 + 131072 + 65536 + 64 * 4 + 32;   // 262432 words
    zero_k<<<(nwords + 255) / 256, 256, 0, stream>>>(ws, nwords);

    hist1_k<<<dim3(48, BS), 256, 0, stream>>>(x, g1, n4);
    scan1_k<<<BS, 128, 0, stream>>>(g1, prp, prefix1, rem1, n);
    hist2_k<<<dim3(48, BS), 256, 0, stream>>>(x, prefix1, g2, n4);
    scan2_k<<<BS, 128, 0, stream>>>(g2, prefix1, rem1, prefix2, rem2);
    hist3_k<<<dim3(48, BS), 256, 0, stream>>>(x, prefix2, g3, n4);
    scan3_k<<<BS, 128, 0, stream>>>(g3, prefix2, rem2, prp, qarr, n);
    mask_k<<<dim3(96, BS), 256, 0, stream>>>((const float4*)x, qarr, prp, (float4*)out, n4);
}